// Round 5
// baseline (79.612 us; speedup 1.0000x reference)
//
#include <hip/hip_runtime.h>
#include <stdint.h>

namespace {

constexpr int kB      = 8;
constexpr int kT      = 4096;
constexpr int kC4     = 256;              // 1024 f32 channels as float4
constexpr int kSegLen = 64;
constexpr int kNSeg   = kT / kSegLen;     // 64
constexpr int kTiles  = kB * kNSeg;       // 512 blocks

constexpr size_t kStOff   = 256;          // ticket counter at d_ws[0]
// state layout: [b][seg][j=0..3][c4=0..255] as u64 = (float_bits<<32) | tag
constexpr size_t kStWords = (size_t)kTiles * 4 * kC4;   // 4 MiB

typedef float f4 __attribute__((ext_vector_type(4)));   // native vec for nt-store

__device__ __forceinline__ uint64_t ld_st(const uint64_t* p) {
    return __hip_atomic_load(p, __ATOMIC_RELAXED, __HIP_MEMORY_SCOPE_AGENT);
}
__device__ __forceinline__ void st_st(uint64_t* p, uint64_t w) {
    __hip_atomic_store(p, w, __ATOMIC_RELAXED, __HIP_MEMORY_SCOPE_AGENT);
}

__global__ __launch_bounds__(256, 2) void fused_scan(const float4* __restrict__ x,
                                                     float4* __restrict__ out,
                                                     uint32_t* __restrict__ ticket,
                                                     uint64_t* __restrict__ st) {
    // Ticket gives scheduling-ordered virtual tile ids: predecessors always started.
    __shared__ uint32_t s_tile;
    if (threadIdx.x == 0) s_tile = atomicAdd(ticket, 1u);
    __syncthreads();
    const uint32_t tile = s_tile;
    const int b   = (int)(tile & 7u);          // interleave the 8 batch chains
    const int seg = (int)(tile >> 3);
    const int c4  = threadIdx.x;

    // Phase 1: stream my [64 x 1024ch] tile, segment sum (allocates x into L3).
    const size_t base = ((size_t)(b * kT + seg * kSegLen)) * kC4 + c4;
    const float4* p = x + base;
    float sx = 0.f, sy = 0.f, sz = 0.f, sw = 0.f;
#pragma unroll 8
    for (int i = 0; i < kSegLen; ++i) {
        const float4 v = p[(size_t)i * kC4];
        sx += v.x; sy += v.y; sz += v.z; sw += v.w;
    }

    // Publish aggregate: one u64 per component, value+tag in the same word.
    {
        const float a[4] = { sx, sy, sz, sw };
#pragma unroll
        for (int j = 0; j < 4; ++j) {
            const size_t idx = ((size_t)((b * kNSeg + seg) * 4 + j) << 8) + c4;
            st_st(st + idx, ((uint64_t)__float_as_uint(a[j]) << 32) | 1u);
        }
    }

    // Phase 2: windowed wait+sum over predecessor segments (8 segs x 4 comp = 32
    // independent loads in flight; all indices compile-time -> stays in VGPRs).
    float ox = 0.f, oy = 0.f, oz = 0.f, ow = 0.f;
    {
        int s = 0;
        while (s < seg) {
            uint64_t v[8][4];
            bool ok = true;
#pragma unroll
            for (int k = 0; k < 8; ++k) {
                const bool in = (s + k) < seg;
#pragma unroll
                for (int j = 0; j < 4; ++j) {
                    const size_t idx =
                        ((size_t)((b * kNSeg + (s + k)) * 4 + j) << 8) + c4;
                    // out-of-range -> tag=1, payload bits 0 (= +0.0f)
                    v[k][j] = in ? ld_st(st + idx) : (uint64_t)1u;
                }
            }
#pragma unroll
            for (int k = 0; k < 8; ++k)
#pragma unroll
                for (int j = 0; j < 4; ++j) ok &= ((uint32_t)v[k][j] != 0u);
            if (!ok) { __builtin_amdgcn_s_sleep(2); continue; }
#pragma unroll
            for (int k = 0; k < 8; ++k) {
                ox += __uint_as_float((uint32_t)(v[k][0] >> 32));
                oy += __uint_as_float((uint32_t)(v[k][1] >> 32));
                oz += __uint_as_float((uint32_t)(v[k][2] >> 32));
                ow += __uint_as_float((uint32_t)(v[k][3] >> 32));
            }
            s += 8;
        }
    }

    // Phase 3: re-read tile (L3-hot), running sum, nontemporal store of mean.
    f4* o = (f4*)(out + base);
    const int t0 = seg * kSegLen;
#pragma unroll 4
    for (int i = 0; i < kSegLen; ++i) {
        const float4 v = p[(size_t)i * kC4];
        ox += v.x; oy += v.y; oz += v.z; ow += v.w;
        const float inv = __builtin_amdgcn_rcpf((float)(t0 + i + 1));
        f4 r;
        r.x = ox * inv; r.y = oy * inv; r.z = oz * inv; r.w = ow * inv;
        __builtin_nontemporal_store(r, o + (size_t)i * kC4);
    }
}

}  // namespace

extern "C" void kernel_launch(void* const* d_in, const int* in_sizes, int n_in,
                              void* d_out, int out_size, void* d_ws, size_t ws_size,
                              hipStream_t stream) {
    const float4* x = (const float4*)d_in[0];
    float4* out     = (float4*)d_out;
    uint32_t* ctr   = (uint32_t*)d_ws;
    uint64_t* st    = (uint64_t*)((char*)d_ws + kStOff);
    // Clear ticket + state tags every launch (graph-capturable, ~4 MiB ≈ 1 µs).
    (void)hipMemsetAsync(d_ws, 0, kStOff + kStWords * sizeof(uint64_t), stream);
    fused_scan<<<kTiles, 256, 0, stream>>>(x, out, ctr, st);
}

// Round 6
// 79.343 us; speedup vs baseline: 1.0034x; 1.0034x over previous
//
#include <hip/hip_runtime.h>
#include <stdint.h>

namespace {

constexpr int kB      = 8;
constexpr int kT      = 4096;
constexpr int kC4     = 256;            // 1024 f32 channels as float4
constexpr int kSegLen = 64;
constexpr int kNSeg   = kT / kSegLen;   // 64 segments per batch chain
constexpr int kTiles  = kB * kNSeg;     // 512 blocks
constexpr int kSub    = 16;             // timesteps per thread (4 quarters x 16)

constexpr size_t kStOff   = 256;        // ticket counter at d_ws[0]
// state: idx = ((b*kNSeg+seg)*4 + j)*256 + c4, u64 = (float_bits<<32)|tag
constexpr size_t kStWords = (size_t)kTiles * 4 * kC4;

typedef float f4 __attribute__((ext_vector_type(4)));

__device__ __forceinline__ uint64_t ld_st(const uint64_t* p) {
    return __hip_atomic_load(p, __ATOMIC_RELAXED, __HIP_MEMORY_SCOPE_AGENT);
}
__device__ __forceinline__ void st_st(uint64_t* p, uint64_t w) {
    __hip_atomic_store(p, w, __ATOMIC_RELAXED, __HIP_MEMORY_SCOPE_AGENT);
}

__global__ __launch_bounds__(1024, 8) void fused_scan(const float4* __restrict__ x,
                                                      float4* __restrict__ out,
                                                      uint32_t* __restrict__ ticket,
                                                      uint64_t* __restrict__ st) {
    __shared__ float4   s_sums[4][kC4];   // quarter sums, 16 KB
    __shared__ float4   s_off[kC4];       // chain offset broadcast, 4 KB
    __shared__ uint32_t s_tile;

    if (threadIdx.x == 0) s_tile = atomicAdd(ticket, 1u);
    __syncthreads();
    const uint32_t tile = s_tile;
    const int b   = (int)(tile & 7u);     // interleave batch chains
    const int seg = (int)(tile >> 3);     // preds have strictly lower tickets
    const int c4  = (int)(threadIdx.x & 255u);
    const int q   = (int)(threadIdx.x >> 8);

    // Phase 1: each thread sums its 16 timesteps (coalesced: lanes = consecutive c4).
    const size_t base = ((size_t)(b * kT + seg * kSegLen + q * kSub)) * kC4 + c4;
    const float4* p = x + base;
    float sx = 0.f, sy = 0.f, sz = 0.f, sw = 0.f;
#pragma unroll 4
    for (int i = 0; i < kSub; ++i) {
        const float4 v = p[(size_t)i * kC4];
        sx += v.x; sy += v.y; sz += v.z; sw += v.w;
    }
    s_sums[q][c4] = make_float4(sx, sy, sz, sw);
    __syncthreads();

    // Exclusive intra-tile offset over quarters (<=3 LDS reads, 2-way alias = free).
    float px = 0.f, py = 0.f, pz = 0.f, pw = 0.f;
    for (int qq = 0; qq < q; ++qq) {
        const float4 v = s_sums[qq][c4];
        px += v.x; py += v.y; pz += v.z; pw += v.w;
    }

    if (q == 3) {
        // Publish tile aggregate = my exclusive offset + my quarter sum.
        const float a[4] = { px + sx, py + sy, pz + sz, pw + sw };
#pragma unroll
        for (int j = 0; j < 4; ++j) {
            const size_t idx = ((size_t)((b * kNSeg + seg) * 4 + j) << 8) + c4;
            st_st(st + idx, ((uint64_t)__float_as_uint(a[j]) << 32) | 1u);
        }
    }
    if (q == 0) {
        // Windowed lookback over predecessor segments (4 segs x 4 comps in flight).
        float ox = 0.f, oy = 0.f, oz = 0.f, ow = 0.f;
        int s = 0;
        while (s < seg) {
            uint64_t v[4][4];
            bool ok = true;
#pragma unroll
            for (int k = 0; k < 4; ++k) {
                const bool in = (s + k) < seg;
#pragma unroll
                for (int j = 0; j < 4; ++j) {
                    const size_t idx =
                        ((size_t)((b * kNSeg + (s + k)) * 4 + j) << 8) + c4;
                    v[k][j] = in ? ld_st(st + idx) : (uint64_t)1u;  // pad: tag=1, +0.0f
                }
            }
#pragma unroll
            for (int k = 0; k < 4; ++k)
#pragma unroll
                for (int j = 0; j < 4; ++j) ok &= ((uint32_t)v[k][j] != 0u);
            if (!ok) { __builtin_amdgcn_s_sleep(2); continue; }
#pragma unroll
            for (int k = 0; k < 4; ++k) {
                ox += __uint_as_float((uint32_t)(v[k][0] >> 32));
                oy += __uint_as_float((uint32_t)(v[k][1] >> 32));
                oz += __uint_as_float((uint32_t)(v[k][2] >> 32));
                ow += __uint_as_float((uint32_t)(v[k][3] >> 32));
            }
            s += 4;
        }
        s_off[c4] = make_float4(ox, oy, oz, ow);
    }
    __syncthreads();

    // Phase 3: running prefix from (chain offset + quarter offset), re-read x
    // (L3-hot after phase 1), nontemporal store of the mean.
    const float4 co = s_off[c4];
    float ox = co.x + px, oy = co.y + py, oz = co.z + pz, ow = co.w + pw;
    f4* o = (f4*)(out + base);
    const int t0 = seg * kSegLen + q * kSub;
#pragma unroll 4
    for (int i = 0; i < kSub; ++i) {
        const float4 v = p[(size_t)i * kC4];
        ox += v.x; oy += v.y; oz += v.z; ow += v.w;
        const float inv = __builtin_amdgcn_rcpf((float)(t0 + i + 1));
        f4 r;
        r.x = ox * inv; r.y = oy * inv; r.z = oz * inv; r.w = ow * inv;
        __builtin_nontemporal_store(r, o + (size_t)i * kC4);
    }
}

}  // namespace

extern "C" void kernel_launch(void* const* d_in, const int* in_sizes, int n_in,
                              void* d_out, int out_size, void* d_ws, size_t ws_size,
                              hipStream_t stream) {
    const float4* x = (const float4*)d_in[0];
    float4* out     = (float4*)d_out;
    uint32_t* ctr   = (uint32_t*)d_ws;
    uint64_t* st    = (uint64_t*)((char*)d_ws + kStOff);
    // Clear ticket + state tags every launch (graph-capturable, ~4 MiB).
    (void)hipMemsetAsync(d_ws, 0, kStOff + kStWords * sizeof(uint64_t), stream);
    fused_scan<<<kTiles, 1024, 0, stream>>>(x, out, ctr, st);
}

// Round 7
// 72.334 us; speedup vs baseline: 1.1006x; 1.0969x over previous
//
#include <hip/hip_runtime.h>
#include <stdint.h>

namespace {

constexpr int kB      = 8;
constexpr int kT      = 4096;
constexpr int kC4     = 256;            // 1024 f32 channels as float4
constexpr int kSegLen = 64;
constexpr int kNSeg   = kT / kSegLen;   // 64 segments per batch chain
constexpr int kTiles  = kB * kNSeg;     // 512 blocks
constexpr int kSub    = 16;             // timesteps per thread (4 quarters x 16)

constexpr size_t kStOff   = 256;        // ticket counter at d_ws[0]
// state: idx = ((b*kNSeg+seg)*4 + j)*256 + c4, u64 = (float_bits<<32)|tag
constexpr size_t kStWords = (size_t)kTiles * 4 * kC4;

typedef float f4 __attribute__((ext_vector_type(4)));

__device__ __forceinline__ uint64_t ld_st(const uint64_t* p) {
    return __hip_atomic_load(p, __ATOMIC_RELAXED, __HIP_MEMORY_SCOPE_AGENT);
}
__device__ __forceinline__ void st_st(uint64_t* p, uint64_t w) {
    __hip_atomic_store(p, w, __ATOMIC_RELAXED, __HIP_MEMORY_SCOPE_AGENT);
}

__global__ __launch_bounds__(1024, 4) void fused_scan(const float4* __restrict__ x,
                                                      float4* __restrict__ out,
                                                      uint32_t* __restrict__ ticket,
                                                      uint64_t* __restrict__ st) {
    __shared__ float4   s_sums[4][kC4];   // quarter sums, 16 KB
    __shared__ float4   s_off[kC4];       // chain offset broadcast, 4 KB
    __shared__ uint32_t s_tile;

    if (threadIdx.x == 0) s_tile = atomicAdd(ticket, 1u);
    __syncthreads();
    const uint32_t tile = s_tile;
    const int b   = (int)(tile & 7u);     // interleave batch chains
    const int seg = (int)(tile >> 3);     // preds have strictly lower tickets
    const int c4  = (int)(threadIdx.x & 255u);
    const int q   = (int)(threadIdx.x >> 8);

    // Phase 1: load my 16 timesteps ONCE into registers (statically indexed ->
    // stays in VGPRs), and compute the quarter sum. 16 loads in flight.
    const size_t base = ((size_t)(b * kT + seg * kSegLen + q * kSub)) * kC4 + c4;
    const float4* p = x + base;
    float4 v[kSub];
#pragma unroll
    for (int i = 0; i < kSub; ++i) v[i] = p[(size_t)i * kC4];

    float sx = 0.f, sy = 0.f, sz = 0.f, sw = 0.f;
#pragma unroll
    for (int i = 0; i < kSub; ++i) {
        sx += v[i].x; sy += v[i].y; sz += v[i].z; sw += v[i].w;
    }
    s_sums[q][c4] = make_float4(sx, sy, sz, sw);
    __syncthreads();

    // Exclusive intra-tile offset over quarters (<=3 LDS reads, 2-way alias = free).
    float px = 0.f, py = 0.f, pz = 0.f, pw = 0.f;
    for (int qq = 0; qq < q; ++qq) {
        const float4 s = s_sums[qq][c4];
        px += s.x; py += s.y; pz += s.z; pw += s.w;
    }

    if (q == 3) {
        // Publish tile aggregate = my exclusive offset + my quarter sum.
        const float a[4] = { px + sx, py + sy, pz + sz, pw + sw };
#pragma unroll
        for (int j = 0; j < 4; ++j) {
            const size_t idx = ((size_t)((b * kNSeg + seg) * 4 + j) << 8) + c4;
            st_st(st + idx, ((uint64_t)__float_as_uint(a[j]) << 32) | 1u);
        }
    }
    if (q == 0) {
        // Windowed lookback over predecessor segments (4 segs x 4 comps in flight).
        float ox = 0.f, oy = 0.f, oz = 0.f, ow = 0.f;
        int s = 0;
        while (s < seg) {
            uint64_t w[4][4];
            bool ok = true;
#pragma unroll
            for (int k = 0; k < 4; ++k) {
                const bool in = (s + k) < seg;
#pragma unroll
                for (int j = 0; j < 4; ++j) {
                    const size_t idx =
                        ((size_t)((b * kNSeg + (s + k)) * 4 + j) << 8) + c4;
                    w[k][j] = in ? ld_st(st + idx) : (uint64_t)1u;  // pad: tag=1, +0.0f
                }
            }
#pragma unroll
            for (int k = 0; k < 4; ++k)
#pragma unroll
                for (int j = 0; j < 4; ++j) ok &= ((uint32_t)w[k][j] != 0u);
            if (!ok) { __builtin_amdgcn_s_sleep(2); continue; }
#pragma unroll
            for (int k = 0; k < 4; ++k) {
                ox += __uint_as_float((uint32_t)(w[k][0] >> 32));
                oy += __uint_as_float((uint32_t)(w[k][1] >> 32));
                oz += __uint_as_float((uint32_t)(w[k][2] >> 32));
                ow += __uint_as_float((uint32_t)(w[k][3] >> 32));
            }
            s += 4;
        }
        s_off[c4] = make_float4(ox, oy, oz, ow);
    }
    __syncthreads();

    // Phase 3: pure store stream from registers — no loads at all.
    const float4 co = s_off[c4];
    float ox = co.x + px, oy = co.y + py, oz = co.z + pz, ow = co.w + pw;
    f4* o = (f4*)(out + base);
    const int t0 = seg * kSegLen + q * kSub;
#pragma unroll
    for (int i = 0; i < kSub; ++i) {
        ox += v[i].x; oy += v[i].y; oz += v[i].z; ow += v[i].w;
        const float inv = __builtin_amdgcn_rcpf((float)(t0 + i + 1));
        f4 r;
        r.x = ox * inv; r.y = oy * inv; r.z = oz * inv; r.w = ow * inv;
        __builtin_nontemporal_store(r, o + (size_t)i * kC4);
    }
}

}  // namespace

extern "C" void kernel_launch(void* const* d_in, const int* in_sizes, int n_in,
                              void* d_out, int out_size, void* d_ws, size_t ws_size,
                              hipStream_t stream) {
    const float4* x = (const float4*)d_in[0];
    float4* out     = (float4*)d_out;
    uint32_t* ctr   = (uint32_t*)d_ws;
    uint64_t* st    = (uint64_t*)((char*)d_ws + kStOff);
    // Clear ticket + state tags every launch (graph-capturable, ~4 MiB).
    (void)hipMemsetAsync(d_ws, 0, kStOff + kStWords * sizeof(uint64_t), stream);
    fused_scan<<<kTiles, 1024, 0, stream>>>(x, out, ctr, st);
}